// Round 6
// baseline (921.535 us; speedup 1.0000x reference)
//
#include <hip/hip_runtime.h>
#include <cmath>

#define D  128   // D_EDGE
#define DR 64    // D_RBF
#define NB 32    // nodes per block in stage1

typedef float fx4 __attribute__((ext_vector_type(4)));  // native vec for nontemporal builtins

__device__ __forceinline__ float ssp_f(float x) {
  // softplus(x) - log(2), numerically stable
  float m = fmaxf(x, 0.0f);
  float t = __expf(-fabsf(x));
  return m + __logf(1.0f + t) - 0.69314718055994531f;
}

// ---------------------------------------------------------------------------
// stage0: W_eff[o][r] = sum_d W_cat[o][d] * W_rbf[d][r]   (128 x 64)
//         b_eff[o]    = b_cat[o] + sum_d b_rbf[d] * W_cat[o][d]
// ---------------------------------------------------------------------------
__global__ __launch_bounds__(256) void stage0_kernel(
    const float* __restrict__ W_rbf, const float* __restrict__ b_rbf,
    const float* __restrict__ W_cat, const float* __restrict__ b_cat,
    float* __restrict__ weff, float* __restrict__ beff)
{
  int gid = blockIdx.x * 256 + threadIdx.x;
  if (gid < D * DR) {
    int o = gid >> 6;      // output channel
    int r = gid & 63;      // rbf channel
    float acc = 0.0f;
    #pragma unroll 8
    for (int d = 0; d < D; ++d)
      acc = fmaf(W_cat[o * 384 + d], W_rbf[d * DR + r], acc);
    weff[gid] = acc;
  }
  if (gid < D) {
    float acc = b_cat[gid];
    #pragma unroll 8
    for (int d = 0; d < D; ++d)
      acc = fmaf(b_rbf[d], W_cat[gid * 384 + d], acc);
    beff[gid] = acc;
  }
}

// ---------------------------------------------------------------------------
// stage1: Pj[n][o] = sum_d vi[n][d] * W_cat[o][128+d]
//         Pi[n][o] = sum_d vi[n][d] * W_cat[o][256+d]
// ---------------------------------------------------------------------------
__global__ __launch_bounds__(256) void stage1_kernel(
    const float* __restrict__ vi, const float* __restrict__ W_cat,
    float* __restrict__ Pj, float* __restrict__ Pi, int N)
{
  __shared__ float vrow[NB * D];
  int base = blockIdx.x * NB;
  int t = threadIdx.x;
  for (int idx = t * 4; idx < NB * D; idx += 1024) {
    int n = base + (idx >> 7);
    float4 v = make_float4(0.f, 0.f, 0.f, 0.f);
    if (n < N) v = *(const float4*)&vi[(long)n * D + (idx & 127)];
    *(float4*)&vrow[idx] = v;
  }
  __syncthreads();

  int o     = t & 127;
  int which = t >> 7;   // 0 -> Pj (cols 128:256), 1 -> Pi (cols 256:384)
  const float* w = W_cat + (long)o * 384 + 128 + which * 128;
  float* P = which ? Pi : Pj;

  float acc[NB];
  #pragma unroll
  for (int n = 0; n < NB; ++n) acc[n] = 0.0f;

  for (int dd = 0; dd < D; dd += 4) {
    float4 wv = *(const float4*)&w[dd];
    #pragma unroll
    for (int n = 0; n < NB; ++n) {
      float4 v = *(const float4*)&vrow[n * D + dd];  // wave-uniform -> broadcast
      acc[n] = fmaf(wv.x, v.x, acc[n]);
      acc[n] = fmaf(wv.y, v.y, acc[n]);
      acc[n] = fmaf(wv.z, v.z, acc[n]);
      acc[n] = fmaf(wv.w, v.w, acc[n]);
    }
  }
  #pragma unroll
  for (int n = 0; n < NB; ++n) {
    int nn = base + n;
    if (nn < N) P[(long)nn * D + o] = acc[n];
  }
}

// ---------------------------------------------------------------------------
// edge kernel: 256 edges/block, 4 output chunks of 32.
// Per chunk: (a) issue ALL 16 gather float4 loads (8 Pj + 8 Pi, batch MLP)
// BEFORE the GEMM so their ~600cy L3 latency hides under ~4096cy of FMA;
// (b) phase-1 lane-per-edge GEMM -> LDS stage (stride 33, conflict-free);
// (c) phase-2 (8 lanes/edge) combine + coalesced nontemporal store.
// NOTE: no min-waves launch bound — needs ~180 live VGPRs (rb=64, gj/gi=64);
// capping VGPRs spills to scratch (R3: 5.4 GB fetch explosion).
// ---------------------------------------------------------------------------
__global__ __launch_bounds__(256) void edge_kernel(
    const float* __restrict__ rbf, const int* __restrict__ eidx,
    const float* __restrict__ weff, const float* __restrict__ beff,
    const float* __restrict__ Pj, const float* __restrict__ Pi,
    float* __restrict__ out, int E)
{
  __shared__ float stage[256 * 33];
  __shared__ int jbuf[256], ibuf[256];

  const int t = threadIdx.x;
  const long base = (long)blockIdx.x * 256;
  const long e = base + t;
  const bool valid = e < (long)E;

  fx4 rb[16];
  if (valid) {
    const fx4* rp = (const fx4*)(rbf + e * DR);
    #pragma unroll
    for (int c = 0; c < 16; ++c) rb[c] = __builtin_nontemporal_load(&rp[c]);
    ibuf[t] = eidx[e];       // edge_index[0] -> h_i -> Pi
    jbuf[t] = eidx[E + e];   // edge_index[1] -> h_j -> Pj
  } else {
    #pragma unroll
    for (int c = 0; c < 16; ++c) rb[c] = (fx4)(0.0f);
    ibuf[t] = 0;
    jbuf[t] = 0;
  }
  __syncthreads();   // indices visible to all phase-2 roles

  // phase-2 role constants; precompute the 8 gather-row offsets once
  const int q  = t >> 3;        // edge-slot within a 32-edge group
  const int oo = (t & 7) * 4;   // float offset within the 32-output chunk
  int ja[8], ia[8];
  #pragma unroll
  for (int p = 0; p < 8; ++p) {
    ja[p] = jbuf[p * 32 + q] * D;   // < 50000*128, fits int
    ia[p] = ibuf[p * 32 + q] * D;
  }

  for (int cb = 0; cb < 4; ++cb) {
    const int ob0 = cb * 32;

    // ---- (a) batched gather issue: 16 loads in flight per thread ----
    fx4 gj[8], gi[8];
    #pragma unroll
    for (int p = 0; p < 8; ++p) {
      gj[p] = *(const fx4*)&Pj[(long)ja[p] + ob0 + oo];
      gi[p] = *(const fx4*)&Pi[(long)ia[p] + ob0 + oo];
    }

    // ---- (b) phase 1: 32 dot-products for own edge, staged to LDS ----
    for (int o = 0; o < 32; o += 4) {
      const int ob = ob0 + o;
      float4 b4 = *(const float4*)&beff[ob];
      float acc0 = b4.x, acc1 = b4.y, acc2 = b4.z, acc3 = b4.w;
      const float4* w0 = (const float4*)&weff[(ob + 0) * DR];
      const float4* w1 = (const float4*)&weff[(ob + 1) * DR];
      const float4* w2 = (const float4*)&weff[(ob + 2) * DR];
      const float4* w3 = (const float4*)&weff[(ob + 3) * DR];
      #pragma unroll
      for (int c = 0; c < 16; ++c) {
        fx4 r4 = rb[c];
        float4 wa = w0[c], wb = w1[c], wc = w2[c], wd = w3[c];
        acc0 = fmaf(wa.x, r4.x, acc0); acc0 = fmaf(wa.y, r4.y, acc0);
        acc0 = fmaf(wa.z, r4.z, acc0); acc0 = fmaf(wa.w, r4.w, acc0);
        acc1 = fmaf(wb.x, r4.x, acc1); acc1 = fmaf(wb.y, r4.y, acc1);
        acc1 = fmaf(wb.z, r4.z, acc1); acc1 = fmaf(wb.w, r4.w, acc1);
        acc2 = fmaf(wc.x, r4.x, acc2); acc2 = fmaf(wc.y, r4.y, acc2);
        acc2 = fmaf(wc.z, r4.z, acc2); acc2 = fmaf(wc.w, r4.w, acc2);
        acc3 = fmaf(wd.x, r4.x, acc3); acc3 = fmaf(wd.y, r4.y, acc3);
        acc3 = fmaf(wd.z, r4.z, acc3); acc3 = fmaf(wd.w, r4.w, acc3);
      }
      stage[t * 33 + o + 0] = acc0;
      stage[t * 33 + o + 1] = acc1;
      stage[t * 33 + o + 2] = acc2;
      stage[t * 33 + o + 3] = acc3;
    }
    __syncthreads();

    // ---- (c) phase 2: combine staged GEMM + landed gathers, store ----
    #pragma unroll
    for (int p = 0; p < 8; ++p) {
      const int el = p * 32 + q;
      const long eg = base + el;
      const float* sp = &stage[el * 33 + oo];
      fx4 o4;
      o4.x = ssp_f(gj[p].x + gi[p].x + sp[0]);
      o4.y = ssp_f(gj[p].y + gi[p].y + sp[1]);
      o4.z = ssp_f(gj[p].z + gi[p].z + sp[2]);
      o4.w = ssp_f(gj[p].w + gi[p].w + sp[3]);
      if (eg < (long)E)
        __builtin_nontemporal_store(o4, (fx4*)&out[eg * D + ob0 + oo]);
    }
    __syncthreads();
  }
}

// ---------------------------------------------------------------------------
// Fallback (only if d_ws is too small for Pj/Pi): 3 additive passes over out.
// ---------------------------------------------------------------------------
template<int K, int WS, int WOFF, bool GATHER, bool INIT, bool FINAL>
__global__ __launch_bounds__(256) void pass_kernel(
    const float* __restrict__ src, const int* __restrict__ gidx,
    const float* __restrict__ W, const float* __restrict__ beff,
    float* __restrict__ out, int E)
{
  int e = blockIdx.x * 256 + threadIdx.x;
  if (e >= E) return;
  long row = GATHER ? (long)gidx[e] : (long)e;

  float4 rv[K / 4];
  const float4* sp = (const float4*)(src + row * K);
  #pragma unroll
  for (int c = 0; c < K / 4; ++c) rv[c] = sp[c];

  float* orow = out + (long)e * D;
  for (int ob = 0; ob < D; ob += 4) {
    float acc[4];
    if (INIT) {
      float4 b4 = *(const float4*)&beff[ob];
      acc[0] = b4.x; acc[1] = b4.y; acc[2] = b4.z; acc[3] = b4.w;
    } else {
      float4 p4 = *(const float4*)&orow[ob];
      acc[0] = p4.x; acc[1] = p4.y; acc[2] = p4.z; acc[3] = p4.w;
    }
    #pragma unroll
    for (int k = 0; k < 4; ++k) {
      const float4* w = (const float4*)&W[(long)(ob + k) * WS + WOFF];
      float a = acc[k];
      #pragma unroll
      for (int c = 0; c < K / 4; ++c) {
        float4 w4 = w[c]; float4 r4 = rv[c];
        a = fmaf(w4.x, r4.x, a); a = fmaf(w4.y, r4.y, a);
        a = fmaf(w4.z, r4.z, a); a = fmaf(w4.w, r4.w, a);
      }
      acc[k] = a;
    }
    float4 o4;
    o4.x = FINAL ? ssp_f(acc[0]) : acc[0];
    o4.y = FINAL ? ssp_f(acc[1]) : acc[1];
    o4.z = FINAL ? ssp_f(acc[2]) : acc[2];
    o4.w = FINAL ? ssp_f(acc[3]) : acc[3];
    *(float4*)&orow[ob] = o4;
  }
}

// ---------------------------------------------------------------------------
extern "C" void kernel_launch(void* const* d_in, const int* in_sizes, int n_in,
                              void* d_out, int out_size, void* d_ws, size_t ws_size,
                              hipStream_t stream)
{
  const float* vi    = (const float*)d_in[0];
  const float* rbf   = (const float*)d_in[1];
  const float* W_rbf = (const float*)d_in[2];
  const float* b_rbf = (const float*)d_in[3];
  const float* W_cat = (const float*)d_in[4];
  const float* b_cat = (const float*)d_in[5];
  const int*   eidx  = (const int*)d_in[6];

  const int N = in_sizes[0] / D;
  const int E = in_sizes[6] / 2;
  float* out = (float*)d_out;

  float* ws   = (float*)d_ws;
  float* weff = ws;                 // 128*64 = 8192 floats
  float* beff = ws + D * DR;        // 128 floats (ends at 8320)
  float* Pj   = ws + 8448;          // N*128 floats, 16B-aligned
  float* Pi   = Pj + (size_t)N * D; // N*128 floats
  size_t need = (8448 + 2 * (size_t)N * D) * sizeof(float);

  stage0_kernel<<<32, 256, 0, stream>>>(W_rbf, b_rbf, W_cat, b_cat, weff, beff);

  int eblocks = (E + 255) / 256;
  if (ws_size >= need) {
    stage1_kernel<<<(N + NB - 1) / NB, 256, 0, stream>>>(vi, W_cat, Pj, Pi, N);
    edge_kernel<<<eblocks, 256, 0, stream>>>(rbf, eidx, weff, beff, Pj, Pi, out, E);
  } else {
    // 3-pass fallback, needs only ~34 KB of ws (weff + beff)
    pass_kernel<DR, DR, 0,  false, true,  false><<<eblocks, 256, 0, stream>>>(rbf, nullptr,  weff,  beff, out, E);
    pass_kernel<D, 384, 128, true, false, false><<<eblocks, 256, 0, stream>>>(vi,  eidx + E, W_cat, beff, out, E);
    pass_kernel<D, 384, 256, true, false, true ><<<eblocks, 256, 0, stream>>>(vi,  eidx,     W_cat, beff, out, E);
  }
}

// Round 7
// 902.832 us; speedup vs baseline: 1.0207x; 1.0207x over previous
//
#include <hip/hip_runtime.h>
#include <cmath>

#define D  128   // D_EDGE
#define DR 64    // D_RBF
#define NB 32    // nodes per block in stage1

typedef float fx4 __attribute__((ext_vector_type(4)));

__device__ __forceinline__ float ssp_f(float x) {
  // softplus(x) - log(2), numerically stable
  float m = fmaxf(x, 0.0f);
  float t = __expf(-fabsf(x));
  return m + __logf(1.0f + t) - 0.69314718055994531f;
}

// ---------------------------------------------------------------------------
// stage0: W_eff[o][r] = sum_d W_cat[o][d] * W_rbf[d][r]   (128 x 64)
//         b_eff[o]    = b_cat[o] + sum_d b_rbf[d] * W_cat[o][d]
// ---------------------------------------------------------------------------
__global__ __launch_bounds__(256) void stage0_kernel(
    const float* __restrict__ W_rbf, const float* __restrict__ b_rbf,
    const float* __restrict__ W_cat, const float* __restrict__ b_cat,
    float* __restrict__ weff, float* __restrict__ beff)
{
  int gid = blockIdx.x * 256 + threadIdx.x;
  if (gid < D * DR) {
    int o = gid >> 6;      // output channel
    int r = gid & 63;      // rbf channel
    float acc = 0.0f;
    #pragma unroll 8
    for (int d = 0; d < D; ++d)
      acc = fmaf(W_cat[o * 384 + d], W_rbf[d * DR + r], acc);
    weff[gid] = acc;
  }
  if (gid < D) {
    float acc = b_cat[gid];
    #pragma unroll 8
    for (int d = 0; d < D; ++d)
      acc = fmaf(b_rbf[d], W_cat[gid * 384 + d], acc);
    beff[gid] = acc;
  }
}

// ---------------------------------------------------------------------------
// stage1: Pj[n][o] = sum_d vi[n][d] * W_cat[o][128+d]
//         Pi[n][o] = sum_d vi[n][d] * W_cat[o][256+d]
// ---------------------------------------------------------------------------
__global__ __launch_bounds__(256) void stage1_kernel(
    const float* __restrict__ vi, const float* __restrict__ W_cat,
    float* __restrict__ Pj, float* __restrict__ Pi, int N)
{
  __shared__ float vrow[NB * D];
  int base = blockIdx.x * NB;
  int t = threadIdx.x;
  for (int idx = t * 4; idx < NB * D; idx += 1024) {
    int n = base + (idx >> 7);
    float4 v = make_float4(0.f, 0.f, 0.f, 0.f);
    if (n < N) v = *(const float4*)&vi[(long)n * D + (idx & 127)];
    *(float4*)&vrow[idx] = v;
  }
  __syncthreads();

  int o     = t & 127;
  int which = t >> 7;   // 0 -> Pj (cols 128:256), 1 -> Pi (cols 256:384)
  const float* w = W_cat + (long)o * 384 + 128 + which * 128;
  float* P = which ? Pi : Pj;

  float acc[NB];
  #pragma unroll
  for (int n = 0; n < NB; ++n) acc[n] = 0.0f;

  for (int dd = 0; dd < D; dd += 4) {
    float4 wv = *(const float4*)&w[dd];
    #pragma unroll
    for (int n = 0; n < NB; ++n) {
      float4 v = *(const float4*)&vrow[n * D + dd];  // wave-uniform -> broadcast
      acc[n] = fmaf(wv.x, v.x, acc[n]);
      acc[n] = fmaf(wv.y, v.y, acc[n]);
      acc[n] = fmaf(wv.z, v.z, acc[n]);
      acc[n] = fmaf(wv.w, v.w, acc[n]);
    }
  }
  #pragma unroll
  for (int n = 0; n < NB; ++n) {
    int nn = base + n;
    if (nn < N) P[(long)nn * D + o] = acc[n];
  }
}

// ---------------------------------------------------------------------------
// edge kernel: 256 edges/block, 4 output chunks of 32.
// Per chunk: issue 8 Pj gathers -> sched_barrier -> GEMM o=0..15 (pure
// VALU+SMEM, ~2048cy hides the ~600cy L3 gather latency) -> issue 8 Pi
// gathers -> sched_barrier -> GEMM o=16..31 -> sync -> combine + store.
// sched_barrier(0) pins the load-issue point: R6 showed the scheduler
// otherwise sinks the gathers to their uses, destroying the prefetch.
// NOTE: no min-waves launch bound — needs ~160 live VGPRs; capping spills
// to scratch (R3: 5.4 GB fetch explosion).
// ---------------------------------------------------------------------------
__global__ __launch_bounds__(256) void edge_kernel(
    const float* __restrict__ rbf, const int* __restrict__ eidx,
    const float* __restrict__ weff, const float* __restrict__ beff,
    const float* __restrict__ Pj, const float* __restrict__ Pi,
    float* __restrict__ out, int E)
{
  __shared__ float stage[256 * 33];
  __shared__ int jbuf[256], ibuf[256];

  const int t = threadIdx.x;
  const long base = (long)blockIdx.x * 256;
  const long e = base + t;
  const bool valid = e < (long)E;

  fx4 rb[16];
  if (valid) {
    const fx4* rp = (const fx4*)(rbf + e * DR);
    #pragma unroll
    for (int c = 0; c < 16; ++c) rb[c] = rp[c];
    ibuf[t] = eidx[e];       // edge_index[0] -> h_i -> Pi
    jbuf[t] = eidx[E + e];   // edge_index[1] -> h_j -> Pj
  } else {
    #pragma unroll
    for (int c = 0; c < 16; ++c) rb[c] = (fx4)(0.0f);
    ibuf[t] = 0;
    jbuf[t] = 0;
  }
  __syncthreads();   // indices visible to all phase-2 roles

  // phase-2 role constants; precompute the 8 gather-row offsets once
  const int q  = t >> 3;        // edge-slot within a 32-edge group
  const int oo = (t & 7) * 4;   // float offset within the 32-output chunk
  int ja[8], ia[8];
  #pragma unroll
  for (int p = 0; p < 8; ++p) {
    ja[p] = jbuf[p * 32 + q] * D;   // < 50000*128, fits int
    ia[p] = ibuf[p * 32 + q] * D;
  }

  for (int cb = 0; cb < 4; ++cb) {
    const int ob0 = cb * 32;
    fx4 gj[8], gi[8];

    // ---- issue Pj gather batch (8 loads in flight) ----
    #pragma unroll
    for (int p = 0; p < 8; ++p)
      gj[p] = *(const fx4*)&Pj[(long)ja[p] + ob0 + oo];
    __builtin_amdgcn_sched_barrier(0);   // pin: loads stay issued here

    // ---- GEMM outputs 0..15 of this chunk (pure VALU + scalar weff) ----
    for (int o = 0; o < 16; o += 4) {
      const int ob = ob0 + o;
      float4 b4 = *(const float4*)&beff[ob];
      float acc0 = b4.x, acc1 = b4.y, acc2 = b4.z, acc3 = b4.w;
      const float4* w0 = (const float4*)&weff[(ob + 0) * DR];
      const float4* w1 = (const float4*)&weff[(ob + 1) * DR];
      const float4* w2 = (const float4*)&weff[(ob + 2) * DR];
      const float4* w3 = (const float4*)&weff[(ob + 3) * DR];
      #pragma unroll
      for (int c = 0; c < 16; ++c) {
        fx4 r4 = rb[c];
        float4 wa = w0[c], wb = w1[c], wc = w2[c], wd = w3[c];
        acc0 = fmaf(wa.x, r4.x, acc0); acc0 = fmaf(wa.y, r4.y, acc0);
        acc0 = fmaf(wa.z, r4.z, acc0); acc0 = fmaf(wa.w, r4.w, acc0);
        acc1 = fmaf(wb.x, r4.x, acc1); acc1 = fmaf(wb.y, r4.y, acc1);
        acc1 = fmaf(wb.z, r4.z, acc1); acc1 = fmaf(wb.w, r4.w, acc1);
        acc2 = fmaf(wc.x, r4.x, acc2); acc2 = fmaf(wc.y, r4.y, acc2);
        acc2 = fmaf(wc.z, r4.z, acc2); acc2 = fmaf(wc.w, r4.w, acc2);
        acc3 = fmaf(wd.x, r4.x, acc3); acc3 = fmaf(wd.y, r4.y, acc3);
        acc3 = fmaf(wd.z, r4.z, acc3); acc3 = fmaf(wd.w, r4.w, acc3);
      }
      stage[t * 33 + o + 0] = acc0;
      stage[t * 33 + o + 1] = acc1;
      stage[t * 33 + o + 2] = acc2;
      stage[t * 33 + o + 3] = acc3;
    }

    // ---- issue Pi gather batch ----
    #pragma unroll
    for (int p = 0; p < 8; ++p)
      gi[p] = *(const fx4*)&Pi[(long)ia[p] + ob0 + oo];
    __builtin_amdgcn_sched_barrier(0);   // pin

    // ---- GEMM outputs 16..31 ----
    for (int o = 16; o < 32; o += 4) {
      const int ob = ob0 + o;
      float4 b4 = *(const float4*)&beff[ob];
      float acc0 = b4.x, acc1 = b4.y, acc2 = b4.z, acc3 = b4.w;
      const float4* w0 = (const float4*)&weff[(ob + 0) * DR];
      const float4* w1 = (const float4*)&weff[(ob + 1) * DR];
      const float4* w2 = (const float4*)&weff[(ob + 2) * DR];
      const float4* w3 = (const float4*)&weff[(ob + 3) * DR];
      #pragma unroll
      for (int c = 0; c < 16; ++c) {
        fx4 r4 = rb[c];
        float4 wa = w0[c], wb = w1[c], wc = w2[c], wd = w3[c];
        acc0 = fmaf(wa.x, r4.x, acc0); acc0 = fmaf(wa.y, r4.y, acc0);
        acc0 = fmaf(wa.z, r4.z, acc0); acc0 = fmaf(wa.w, r4.w, acc0);
        acc1 = fmaf(wb.x, r4.x, acc1); acc1 = fmaf(wb.y, r4.y, acc1);
        acc1 = fmaf(wb.z, r4.z, acc1); acc1 = fmaf(wb.w, r4.w, acc1);
        acc2 = fmaf(wc.x, r4.x, acc2); acc2 = fmaf(wc.y, r4.y, acc2);
        acc2 = fmaf(wc.z, r4.z, acc2); acc2 = fmaf(wc.w, r4.w, acc2);
        acc3 = fmaf(wd.x, r4.x, acc3); acc3 = fmaf(wd.y, r4.y, acc3);
        acc3 = fmaf(wd.z, r4.z, acc3); acc3 = fmaf(wd.w, r4.w, acc3);
      }
      stage[t * 33 + o + 0] = acc0;
      stage[t * 33 + o + 1] = acc1;
      stage[t * 33 + o + 2] = acc2;
      stage[t * 33 + o + 3] = acc3;
    }
    __syncthreads();

    // ---- phase 2: combine staged GEMM + landed gathers, store ----
    #pragma unroll
    for (int p = 0; p < 8; ++p) {
      const int el = p * 32 + q;
      const long eg = base + el;
      const float* sp = &stage[el * 33 + oo];
      fx4 o4;
      o4.x = ssp_f(gj[p].x + gi[p].x + sp[0]);
      o4.y = ssp_f(gj[p].y + gi[p].y + sp[1]);
      o4.z = ssp_f(gj[p].z + gi[p].z + sp[2]);
      o4.w = ssp_f(gj[p].w + gi[p].w + sp[3]);
      if (eg < (long)E) *(fx4*)&out[eg * D + ob0 + oo] = o4;
    }
    __syncthreads();
  }
}

// ---------------------------------------------------------------------------
// Fallback (only if d_ws is too small for Pj/Pi): 3 additive passes over out.
// ---------------------------------------------------------------------------
template<int K, int WS, int WOFF, bool GATHER, bool INIT, bool FINAL>
__global__ __launch_bounds__(256) void pass_kernel(
    const float* __restrict__ src, const int* __restrict__ gidx,
    const float* __restrict__ W, const float* __restrict__ beff,
    float* __restrict__ out, int E)
{
  int e = blockIdx.x * 256 + threadIdx.x;
  if (e >= E) return;
  long row = GATHER ? (long)gidx[e] : (long)e;

  float4 rv[K / 4];
  const float4* sp = (const float4*)(src + row * K);
  #pragma unroll
  for (int c = 0; c < K / 4; ++c) rv[c] = sp[c];

  float* orow = out + (long)e * D;
  for (int ob = 0; ob < D; ob += 4) {
    float acc[4];
    if (INIT) {
      float4 b4 = *(const float4*)&beff[ob];
      acc[0] = b4.x; acc[1] = b4.y; acc[2] = b4.z; acc[3] = b4.w;
    } else {
      float4 p4 = *(const float4*)&orow[ob];
      acc[0] = p4.x; acc[1] = p4.y; acc[2] = p4.z; acc[3] = p4.w;
    }
    #pragma unroll
    for (int k = 0; k < 4; ++k) {
      const float4* w = (const float4*)&W[(long)(ob + k) * WS + WOFF];
      float a = acc[k];
      #pragma unroll
      for (int c = 0; c < K / 4; ++c) {
        float4 w4 = w[c]; float4 r4 = rv[c];
        a = fmaf(w4.x, r4.x, a); a = fmaf(w4.y, r4.y, a);
        a = fmaf(w4.z, r4.z, a); a = fmaf(w4.w, r4.w, a);
      }
      acc[k] = a;
    }
    float4 o4;
    o4.x = FINAL ? ssp_f(acc[0]) : acc[0];
    o4.y = FINAL ? ssp_f(acc[1]) : acc[1];
    o4.z = FINAL ? ssp_f(acc[2]) : acc[2];
    o4.w = FINAL ? ssp_f(acc[3]) : acc[3];
    *(float4*)&orow[ob] = o4;
  }
}

// ---------------------------------------------------------------------------
extern "C" void kernel_launch(void* const* d_in, const int* in_sizes, int n_in,
                              void* d_out, int out_size, void* d_ws, size_t ws_size,
                              hipStream_t stream)
{
  const float* vi    = (const float*)d_in[0];
  const float* rbf   = (const float*)d_in[1];
  const float* W_rbf = (const float*)d_in[2];
  const float* b_rbf = (const float*)d_in[3];
  const float* W_cat = (const float*)d_in[4];
  const float* b_cat = (const float*)d_in[5];
  const int*   eidx  = (const int*)d_in[6];

  const int N = in_sizes[0] / D;
  const int E = in_sizes[6] / 2;
  float* out = (float*)d_out;

  float* ws   = (float*)d_ws;
  float* weff = ws;                 // 128*64 = 8192 floats
  float* beff = ws + D * DR;        // 128 floats (ends at 8320)
  float* Pj   = ws + 8448;          // N*128 floats, 16B-aligned
  float* Pi   = Pj + (size_t)N * D; // N*128 floats
  size_t need = (8448 + 2 * (size_t)N * D) * sizeof(float);

  stage0_kernel<<<32, 256, 0, stream>>>(W_rbf, b_rbf, W_cat, b_cat, weff, beff);

  int eblocks = (E + 255) / 256;
  if (ws_size >= need) {
    stage1_kernel<<<(N + NB - 1) / NB, 256, 0, stream>>>(vi, W_cat, Pj, Pi, N);
    edge_kernel<<<eblocks, 256, 0, stream>>>(rbf, eidx, weff, beff, Pj, Pi, out, E);
  } else {
    // 3-pass fallback, needs only ~34 KB of ws (weff + beff)
    pass_kernel<DR, DR, 0,  false, true,  false><<<eblocks, 256, 0, stream>>>(rbf, nullptr,  weff,  beff, out, E);
    pass_kernel<D, 384, 128, true, false, false><<<eblocks, 256, 0, stream>>>(vi,  eidx + E, W_cat, beff, out, E);
    pass_kernel<D, 384, 256, true, false, true ><<<eblocks, 256, 0, stream>>>(vi,  eidx,     W_cat, beff, out, E);
  }
}

// Round 8
// 713.607 us; speedup vs baseline: 1.2914x; 1.2652x over previous
//
#include <hip/hip_runtime.h>
#include <cmath>

#define D  128   // D_EDGE
#define DR 64    // D_RBF
#define NB 32    // nodes per block in stage1

typedef float fx4 __attribute__((ext_vector_type(4)));

__device__ __forceinline__ float ssp_f(float x) {
  // softplus(x) - log(2), numerically stable
  float m = fmaxf(x, 0.0f);
  float t = __expf(-fabsf(x));
  return m + __logf(1.0f + t) - 0.69314718055994531f;
}

// ---------------------------------------------------------------------------
// stage0: W_eff[o][r] = sum_d W_cat[o][d] * W_rbf[d][r]   (128 x 64)
//         b_eff[o]    = b_cat[o] + sum_d b_rbf[d] * W_cat[o][d]
// ---------------------------------------------------------------------------
__global__ __launch_bounds__(256) void stage0_kernel(
    const float* __restrict__ W_rbf, const float* __restrict__ b_rbf,
    const float* __restrict__ W_cat, const float* __restrict__ b_cat,
    float* __restrict__ weff, float* __restrict__ beff)
{
  int gid = blockIdx.x * 256 + threadIdx.x;
  if (gid < D * DR) {
    int o = gid >> 6;      // output channel
    int r = gid & 63;      // rbf channel
    float acc = 0.0f;
    #pragma unroll 8
    for (int d = 0; d < D; ++d)
      acc = fmaf(W_cat[o * 384 + d], W_rbf[d * DR + r], acc);
    weff[gid] = acc;
  }
  if (gid < D) {
    float acc = b_cat[gid];
    #pragma unroll 8
    for (int d = 0; d < D; ++d)
      acc = fmaf(b_rbf[d], W_cat[gid * 384 + d], acc);
    beff[gid] = acc;
  }
}

// ---------------------------------------------------------------------------
// stage1: Pj[n][o] = sum_d vi[n][d] * W_cat[o][128+d]
//         Pi[n][o] = sum_d vi[n][d] * W_cat[o][256+d]
// ---------------------------------------------------------------------------
__global__ __launch_bounds__(256) void stage1_kernel(
    const float* __restrict__ vi, const float* __restrict__ W_cat,
    float* __restrict__ Pj, float* __restrict__ Pi, int N)
{
  __shared__ float vrow[NB * D];
  int base = blockIdx.x * NB;
  int t = threadIdx.x;
  for (int idx = t * 4; idx < NB * D; idx += 1024) {
    int n = base + (idx >> 7);
    float4 v = make_float4(0.f, 0.f, 0.f, 0.f);
    if (n < N) v = *(const float4*)&vi[(long)n * D + (idx & 127)];
    *(float4*)&vrow[idx] = v;
  }
  __syncthreads();

  int o     = t & 127;
  int which = t >> 7;   // 0 -> Pj (cols 128:256), 1 -> Pi (cols 256:384)
  const float* w = W_cat + (long)o * 384 + 128 + which * 128;
  float* P = which ? Pi : Pj;

  float acc[NB];
  #pragma unroll
  for (int n = 0; n < NB; ++n) acc[n] = 0.0f;

  for (int dd = 0; dd < D; dd += 4) {
    float4 wv = *(const float4*)&w[dd];
    #pragma unroll
    for (int n = 0; n < NB; ++n) {
      float4 v = *(const float4*)&vrow[n * D + dd];  // wave-uniform -> broadcast
      acc[n] = fmaf(wv.x, v.x, acc[n]);
      acc[n] = fmaf(wv.y, v.y, acc[n]);
      acc[n] = fmaf(wv.z, v.z, acc[n]);
      acc[n] = fmaf(wv.w, v.w, acc[n]);
    }
  }
  #pragma unroll
  for (int n = 0; n < NB; ++n) {
    int nn = base + n;
    if (nn < N) P[(long)nn * D + o] = acc[n];
  }
}

// ---------------------------------------------------------------------------
// Kernel A: g[e][:] = rbf[e] @ W_eff^T + b_eff   (raw pre-activation to out)
// Lane-per-edge; W_eff staged in LDS (broadcast reads, no scalar-cache
// thrash); 32-channel chunks staged in LDS -> coalesced full-line stores.
// No gathers, no barrier-coupled latency -> VALU-bound.
// ---------------------------------------------------------------------------
__global__ __launch_bounds__(256) void gemm_kernel(
    const float* __restrict__ rbf, const float* __restrict__ weff,
    const float* __restrict__ beff, float* __restrict__ g, int E)
{
  __shared__ float W[D * DR];       // 32 KB
  __shared__ float bsh[D];
  __shared__ float stage[256 * 33]; // 33.8 KB

  const int t = threadIdx.x;
  const long base = (long)blockIdx.x * 256;
  const long e = base + t;
  const bool valid = e < (long)E;

  // cooperative load of W_eff (+ bias) into LDS, coalesced
  for (int idx = t * 4; idx < D * DR; idx += 1024)
    *(float4*)&W[idx] = *(const float4*)&weff[idx];
  if (t < 32) *(float4*)&bsh[t * 4] = *(const float4*)&beff[t * 4];

  fx4 rb[16];
  if (valid) {
    const fx4* rp = (const fx4*)(rbf + e * DR);
    #pragma unroll
    for (int c = 0; c < 16; ++c) rb[c] = __builtin_nontemporal_load(&rp[c]);
  } else {
    #pragma unroll
    for (int c = 0; c < 16; ++c) rb[c] = (fx4)(0.0f);
  }
  __syncthreads();

  const int q  = t >> 3;        // edge-slot within a 32-edge group (store phase)
  const int oo = (t & 7) * 4;   // float offset within 32-chunk (store phase)

  for (int cb = 0; cb < 4; ++cb) {
    const int ob0 = cb * 32;

    // ---- GEMM: 32 channels for own edge, weights broadcast from LDS ----
    for (int o = 0; o < 32; o += 4) {
      const int ob = ob0 + o;
      float acc0 = bsh[ob + 0], acc1 = bsh[ob + 1];
      float acc2 = bsh[ob + 2], acc3 = bsh[ob + 3];
      const float4* w0 = (const float4*)&W[(ob + 0) * DR];
      const float4* w1 = (const float4*)&W[(ob + 1) * DR];
      const float4* w2 = (const float4*)&W[(ob + 2) * DR];
      const float4* w3 = (const float4*)&W[(ob + 3) * DR];
      #pragma unroll
      for (int c = 0; c < 16; ++c) {
        fx4 r4 = rb[c];
        float4 wa = w0[c], wb = w1[c], wc = w2[c], wd = w3[c];
        acc0 = fmaf(wa.x, r4.x, acc0); acc0 = fmaf(wa.y, r4.y, acc0);
        acc0 = fmaf(wa.z, r4.z, acc0); acc0 = fmaf(wa.w, r4.w, acc0);
        acc1 = fmaf(wb.x, r4.x, acc1); acc1 = fmaf(wb.y, r4.y, acc1);
        acc1 = fmaf(wb.z, r4.z, acc1); acc1 = fmaf(wb.w, r4.w, acc1);
        acc2 = fmaf(wc.x, r4.x, acc2); acc2 = fmaf(wc.y, r4.y, acc2);
        acc2 = fmaf(wc.z, r4.z, acc2); acc2 = fmaf(wc.w, r4.w, acc2);
        acc3 = fmaf(wd.x, r4.x, acc3); acc3 = fmaf(wd.y, r4.y, acc3);
        acc3 = fmaf(wd.z, r4.z, acc3); acc3 = fmaf(wd.w, r4.w, acc3);
      }
      stage[t * 33 + o + 0] = acc0;
      stage[t * 33 + o + 1] = acc1;
      stage[t * 33 + o + 2] = acc2;
      stage[t * 33 + o + 3] = acc3;
    }
    __syncthreads();

    // ---- coalesced store: 8 lanes cover one edge's 128B chunk ----
    #pragma unroll
    for (int p = 0; p < 8; ++p) {
      const int el = p * 32 + q;
      const long eg = base + el;
      const float* sp = &stage[el * 33 + oo];
      fx4 o4 = { sp[0], sp[1], sp[2], sp[3] };
      if (eg < (long)E)
        __builtin_nontemporal_store(o4, (fx4*)&g[eg * D + ob0 + oo]);
    }
    __syncthreads();
  }
}

// ---------------------------------------------------------------------------
// Kernel B: out[e][c] = ssp(out[e][c] + Pj[j[e]][c] + Pi[i[e]][c])
// Pure memory kernel: low VGPR, high occupancy, batch=4 items/thread for
// MLP (12 data loads in flight). NT on the g stream (read-once/write-once)
// keeps L2 free for the 51 MB Pj/Pi tables.
// Item k: e = k>>5, oo = (k&31)*4; consecutive threads -> consecutive
// addresses (full-line gathers: 32 lanes cover one edge's 512B row).
// ---------------------------------------------------------------------------
#define BBATCH 4
__global__ __launch_bounds__(256) void combine_kernel(
    const int* __restrict__ eidx,
    const float* __restrict__ Pj, const float* __restrict__ Pi,
    float* out, int E)
{
  const long T = (long)gridDim.x * 256;        // total threads
  const long items = (long)E * 32;
  const long gid = (long)blockIdx.x * 256 + threadIdx.x;

  long e[BBATCH]; int oo[BBATCH]; int jj[BBATCH], ii[BBATCH];
  bool ok[BBATCH];
  #pragma unroll
  for (int b = 0; b < BBATCH; ++b) {
    const long k = gid + b * T;
    ok[b] = k < items;
    const long kc = ok[b] ? k : 0;
    e[b]  = kc >> 5;
    oo[b] = (int)(kc & 31) * 4;
    ii[b] = eidx[e[b]];          // edge_index[0] -> h_i -> Pi
    jj[b] = eidx[E + e[b]];      // edge_index[1] -> h_j -> Pj
  }

  fx4 pj[BBATCH], pi[BBATCH], gg[BBATCH];
  #pragma unroll
  for (int b = 0; b < BBATCH; ++b) {
    pj[b] = *(const fx4*)&Pj[(long)jj[b] * D + oo[b]];
    pi[b] = *(const fx4*)&Pi[(long)ii[b] * D + oo[b]];
  }
  #pragma unroll
  for (int b = 0; b < BBATCH; ++b)
    gg[b] = __builtin_nontemporal_load((const fx4*)&out[e[b] * D + oo[b]]);

  #pragma unroll
  for (int b = 0; b < BBATCH; ++b) {
    fx4 o4;
    o4.x = ssp_f(gg[b].x + pj[b].x + pi[b].x);
    o4.y = ssp_f(gg[b].y + pj[b].y + pi[b].y);
    o4.z = ssp_f(gg[b].z + pj[b].z + pi[b].z);
    o4.w = ssp_f(gg[b].w + pj[b].w + pi[b].w);
    if (ok[b])
      __builtin_nontemporal_store(o4, (fx4*)&out[e[b] * D + oo[b]]);
  }
}

// ---------------------------------------------------------------------------
// Fallback (only if d_ws is too small for Pj/Pi): 3 additive passes over out.
// ---------------------------------------------------------------------------
template<int K, int WS, int WOFF, bool GATHER, bool INIT, bool FINAL>
__global__ __launch_bounds__(256) void pass_kernel(
    const float* __restrict__ src, const int* __restrict__ gidx,
    const float* __restrict__ W, const float* __restrict__ beff,
    float* __restrict__ out, int E)
{
  int e = blockIdx.x * 256 + threadIdx.x;
  if (e >= E) return;
  long row = GATHER ? (long)gidx[e] : (long)e;

  float4 rv[K / 4];
  const float4* sp = (const float4*)(src + row * K);
  #pragma unroll
  for (int c = 0; c < K / 4; ++c) rv[c] = sp[c];

  float* orow = out + (long)e * D;
  for (int ob = 0; ob < D; ob += 4) {
    float acc[4];
    if (INIT) {
      float4 b4 = *(const float4*)&beff[ob];
      acc[0] = b4.x; acc[1] = b4.y; acc[2] = b4.z; acc[3] = b4.w;
    } else {
      float4 p4 = *(const float4*)&orow[ob];
      acc[0] = p4.x; acc[1] = p4.y; acc[2] = p4.z; acc[3] = p4.w;
    }
    #pragma unroll
    for (int k = 0; k < 4; ++k) {
      const float4* w = (const float4*)&W[(long)(ob + k) * WS + WOFF];
      float a = acc[k];
      #pragma unroll
      for (int c = 0; c < K / 4; ++c) {
        float4 w4 = w[c]; float4 r4 = rv[c];
        a = fmaf(w4.x, r4.x, a); a = fmaf(w4.y, r4.y, a);
        a = fmaf(w4.z, r4.z, a); a = fmaf(w4.w, r4.w, a);
      }
      acc[k] = a;
    }
    float4 o4;
    o4.x = FINAL ? ssp_f(acc[0]) : acc[0];
    o4.y = FINAL ? ssp_f(acc[1]) : acc[1];
    o4.z = FINAL ? ssp_f(acc[2]) : acc[2];
    o4.w = FINAL ? ssp_f(acc[3]) : acc[3];
    *(float4*)&orow[ob] = o4;
  }
}

// ---------------------------------------------------------------------------
extern "C" void kernel_launch(void* const* d_in, const int* in_sizes, int n_in,
                              void* d_out, int out_size, void* d_ws, size_t ws_size,
                              hipStream_t stream)
{
  const float* vi    = (const float*)d_in[0];
  const float* rbf   = (const float*)d_in[1];
  const float* W_rbf = (const float*)d_in[2];
  const float* b_rbf = (const float*)d_in[3];
  const float* W_cat = (const float*)d_in[4];
  const float* b_cat = (const float*)d_in[5];
  const int*   eidx  = (const int*)d_in[6];

  const int N = in_sizes[0] / D;
  const int E = in_sizes[6] / 2;
  float* out = (float*)d_out;

  float* ws   = (float*)d_ws;
  float* weff = ws;                 // 128*64 = 8192 floats
  float* beff = ws + D * DR;        // 128 floats (ends at 8320)
  float* Pj   = ws + 8448;          // N*128 floats, 16B-aligned
  float* Pi   = Pj + (size_t)N * D; // N*128 floats
  size_t need = (8448 + 2 * (size_t)N * D) * sizeof(float);

  stage0_kernel<<<32, 256, 0, stream>>>(W_rbf, b_rbf, W_cat, b_cat, weff, beff);

  int eblocks = (E + 255) / 256;
  if (ws_size >= need) {
    stage1_kernel<<<(N + NB - 1) / NB, 256, 0, stream>>>(vi, W_cat, Pj, Pi, N);
    gemm_kernel<<<eblocks, 256, 0, stream>>>(rbf, weff, beff, out, E);
    long items = (long)E * 32;
    int cblocks = (int)((items + 256L * BBATCH - 1) / (256L * BBATCH));
    combine_kernel<<<cblocks, 256, 0, stream>>>(eidx, Pj, Pi, out, E);
  } else {
    // 3-pass fallback, needs only ~34 KB of ws (weff + beff)
    pass_kernel<DR, DR, 0,  false, true,  false><<<eblocks, 256, 0, stream>>>(rbf, nullptr,  weff,  beff, out, E);
    pass_kernel<D, 384, 128, true, false, false><<<eblocks, 256, 0, stream>>>(vi,  eidx + E, W_cat, beff, out, E);
    pass_kernel<D, 384, 256, true, false, true ><<<eblocks, 256, 0, stream>>>(vi,  eidx,     W_cat, beff, out, E);
  }
}

// Round 9
// 483.869 us; speedup vs baseline: 1.9045x; 1.4748x over previous
//
#include <hip/hip_runtime.h>
#include <cmath>

#define D  128   // D_EDGE
#define DR 64    // D_RBF
#define NB 32    // nodes per block in stage1

typedef float fx4 __attribute__((ext_vector_type(4)));

__device__ __forceinline__ float ssp_f(float x) {
  // softplus(x) - log(2), numerically stable
  float m = fmaxf(x, 0.0f);
  float t = __expf(-fabsf(x));
  return m + __logf(1.0f + t) - 0.69314718055994531f;
}

// ---------------------------------------------------------------------------
// stage0: W_eff[o][r] = sum_d W_cat[o][d] * W_rbf[d][r]   (128 x 64)
//         b_eff[o]    = b_cat[o] + sum_d b_rbf[d] * W_cat[o][d]
// ---------------------------------------------------------------------------
__global__ __launch_bounds__(256) void stage0_kernel(
    const float* __restrict__ W_rbf, const float* __restrict__ b_rbf,
    const float* __restrict__ W_cat, const float* __restrict__ b_cat,
    float* __restrict__ weff, float* __restrict__ beff)
{
  int gid = blockIdx.x * 256 + threadIdx.x;
  if (gid < D * DR) {
    int o = gid >> 6;
    int r = gid & 63;
    float acc = 0.0f;
    #pragma unroll 8
    for (int d = 0; d < D; ++d)
      acc = fmaf(W_cat[o * 384 + d], W_rbf[d * DR + r], acc);
    weff[gid] = acc;
  }
  if (gid < D) {
    float acc = b_cat[gid];
    #pragma unroll 8
    for (int d = 0; d < D; ++d)
      acc = fmaf(b_rbf[d], W_cat[gid * 384 + d], acc);
    beff[gid] = acc;
  }
}

// ---------------------------------------------------------------------------
// stage1: Pj[n][o] = sum_d vi[n][d] * W_cat[o][128+d]
//         Pi[n][o] = sum_d vi[n][d] * W_cat[o][256+d]
// ---------------------------------------------------------------------------
__global__ __launch_bounds__(256) void stage1_kernel(
    const float* __restrict__ vi, const float* __restrict__ W_cat,
    float* __restrict__ Pj, float* __restrict__ Pi, int N)
{
  __shared__ float vrow[NB * D];
  int base = blockIdx.x * NB;
  int t = threadIdx.x;
  for (int idx = t * 4; idx < NB * D; idx += 1024) {
    int n = base + (idx >> 7);
    float4 v = make_float4(0.f, 0.f, 0.f, 0.f);
    if (n < N) v = *(const float4*)&vi[(long)n * D + (idx & 127)];
    *(float4*)&vrow[idx] = v;
  }
  __syncthreads();

  int o     = t & 127;
  int which = t >> 7;
  const float* w = W_cat + (long)o * 384 + 128 + which * 128;
  float* P = which ? Pi : Pj;

  float acc[NB];
  #pragma unroll
  for (int n = 0; n < NB; ++n) acc[n] = 0.0f;

  for (int dd = 0; dd < D; dd += 4) {
    float4 wv = *(const float4*)&w[dd];
    #pragma unroll
    for (int n = 0; n < NB; ++n) {
      float4 v = *(const float4*)&vrow[n * D + dd];
      acc[n] = fmaf(wv.x, v.x, acc[n]);
      acc[n] = fmaf(wv.y, v.y, acc[n]);
      acc[n] = fmaf(wv.z, v.z, acc[n]);
      acc[n] = fmaf(wv.w, v.w, acc[n]);
    }
  }
  #pragma unroll
  for (int n = 0; n < NB; ++n) {
    int nn = base + n;
    if (nn < N) P[(long)nn * D + o] = acc[n];
  }
}

// ---------------------------------------------------------------------------
// Fused transposed kernel. Wave-autonomous (NO barriers):
//   lane = output channel pair (o = lane, o+64); W_eff rows held in VGPRs.
//   wave owns a 256-edge strip, processed in 32 groups of 8 edges.
// Per group: rbf staged coalesced -> wave-private LDS (read back as uniform
// broadcasts, free); Pj/Pi gathers are coalesced 256B row reads; stores
// coalesced. Pipeline: indices 2 groups ahead, gathers + rbf 1 group ahead
// -> every load hides under a full ~2200cy FMA phase.
// ---------------------------------------------------------------------------
__device__ __forceinline__ void idx_load(const int* __restrict__ eidx, int E,
                                         long wbase, int g, int lane,
                                         int& jv, int& iv) {
  long gb = wbase + (long)g * 8 + (lane & 7);
  if (gb > (long)E - 1) gb = (long)E - 1;
  jv = eidx[(long)E + gb];   // edge_index[1] -> h_j -> Pj
  iv = eidx[gb];             // edge_index[0] -> h_i -> Pi
}

__device__ __forceinline__ void gather8(const float* __restrict__ Pj,
                                        const float* __restrict__ Pi,
                                        int lane, int jv, int iv,
                                        float* gj0, float* gj1,
                                        float* gi0, float* gi1) {
  #pragma unroll
  for (int e2 = 0; e2 < 8; ++e2) {
    int j = __builtin_amdgcn_readlane(jv, e2);
    int i = __builtin_amdgcn_readlane(iv, e2);
    gj0[e2] = Pj[(long)j * D + lane];
    gj1[e2] = Pj[(long)j * D + 64 + lane];
    gi0[e2] = Pi[(long)i * D + lane];
    gi1[e2] = Pi[(long)i * D + 64 + lane];
  }
}

__device__ __forceinline__ void stage_load(const float* __restrict__ rbf, int E,
                                           long wbase, int g, int lane,
                                           fx4& s0, fx4& s1) {
  long sb = wbase + (long)g * 8;
  if (sb + 8 > (long)E) sb = (long)E - 8;   // E >= 8 always here
  const float* src = &rbf[sb * DR];
  s0 = *(const fx4*)&src[lane * 8];
  s1 = *(const fx4*)&src[lane * 8 + 4];
}

__device__ __forceinline__ void compute_group(
    const float* buf, const fx4* w0q, const fx4* w1q, float b0, float b1,
    const float* gj0, const float* gj1, const float* gi0, const float* gi1,
    float* __restrict__ out, int E, long wbase, int g, int lane) {
  #pragma unroll
  for (int e2 = 0; e2 < 8; ++e2) {
    const float* row = &buf[e2 * DR];
    float acc0 = b0, acc1 = b1;
    #pragma unroll
    for (int c = 0; c < 16; ++c) {
      fx4 r = *(const fx4*)&row[c * 4];   // wave-uniform -> LDS broadcast
      fx4 wa = w0q[c], wb = w1q[c];
      acc0 = fmaf(wa.x, r.x, acc0); acc0 = fmaf(wa.y, r.y, acc0);
      acc0 = fmaf(wa.z, r.z, acc0); acc0 = fmaf(wa.w, r.w, acc0);
      acc1 = fmaf(wb.x, r.x, acc1); acc1 = fmaf(wb.y, r.y, acc1);
      acc1 = fmaf(wb.z, r.z, acc1); acc1 = fmaf(wb.w, r.w, acc1);
    }
    long ge = wbase + (long)g * 8 + e2;
    if (ge < (long)E) {
      out[ge * D + lane]      = ssp_f(acc0 + gj0[e2] + gi0[e2]);
      out[ge * D + 64 + lane] = ssp_f(acc1 + gj1[e2] + gi1[e2]);
    }
  }
}

__global__ __launch_bounds__(256) void fused_kernel(
    const float* __restrict__ rbf, const int* __restrict__ eidx,
    const float* __restrict__ weff, const float* __restrict__ beff,
    const float* __restrict__ Pj, const float* __restrict__ Pi,
    float* __restrict__ out, int E)
{
  __shared__ fx4 lds4[4 * 2 * 128];   // 4 waves x 2 bufs x 512 floats = 16 KB

  const int t = threadIdx.x;
  const int w = t >> 6, lane = t & 63;
  const long wbase = ((long)blockIdx.x * 4 + w) * 256;
  if (wbase >= (long)E) return;

  // weights: lane holds W_eff rows `lane` and `lane+64` (128 VGPRs)
  fx4 w0q[16], w1q[16];
  #pragma unroll
  for (int c = 0; c < 16; ++c) w0q[c] = *(const fx4*)&weff[lane * DR + c * 4];
  #pragma unroll
  for (int c = 0; c < 16; ++c) w1q[c] = *(const fx4*)&weff[(lane + 64) * DR + c * 4];
  const float b0 = beff[lane], b1 = beff[lane + 64];

  float* buf0 = (float*)&lds4[(w * 2 + 0) * 128];
  float* buf1 = (float*)&lds4[(w * 2 + 1) * 128];

  int jvA, ivA, jvB, ivB;
  float gj0A[8], gj1A[8], gi0A[8], gi1A[8];
  float gj0B[8], gj1B[8], gi0B[8], gi1B[8];
  fx4 sA0, sA1, sB0, sB1;

  // prologue
  idx_load(eidx, E, wbase, 0, lane, jvA, ivA);
  idx_load(eidx, E, wbase, 1, lane, jvB, ivB);
  stage_load(rbf, E, wbase, 0, lane, sA0, sA1);
  gather8(Pj, Pi, lane, jvA, ivA, gj0A, gj1A, gi0A, gi1A);   // group 0 in flight
  *(fx4*)&buf0[lane * 8] = sA0;
  *(fx4*)&buf0[lane * 8 + 4] = sA1;

  for (int g = 0; g < 32; g += 2) {
    // issue group g+1 (rbf + gathers; iB loaded one phase ago)
    stage_load(rbf, E, wbase, g + 1, lane, sB0, sB1);
    gather8(Pj, Pi, lane, jvB, ivB, gj0B, gj1B, gi0B, gi1B);
    // index prefetch for group g+2 (2 phases ahead of its readlane use)
    idx_load(eidx, E, wbase, g + 2, lane, jvA, ivA);

    compute_group(buf0, w0q, w1q, b0, b1, gj0A, gj1A, gi0A, gi1A,
                  out, E, wbase, g, lane);

    *(fx4*)&buf1[lane * 8] = sB0;       // rbf g+1 landed during compute
    *(fx4*)&buf1[lane * 8 + 4] = sB1;

    // issue group g+2
    stage_load(rbf, E, wbase, g + 2, lane, sA0, sA1);
    gather8(Pj, Pi, lane, jvA, ivA, gj0A, gj1A, gi0A, gi1A);
    idx_load(eidx, E, wbase, g + 3, lane, jvB, ivB);

    compute_group(buf1, w0q, w1q, b0, b1, gj0B, gj1B, gi0B, gi1B,
                  out, E, wbase, g + 1, lane);

    *(fx4*)&buf0[lane * 8] = sA0;
    *(fx4*)&buf0[lane * 8 + 4] = sA1;
  }
}

// ---------------------------------------------------------------------------
// Fallback (only if d_ws is too small for Pj/Pi): 3 additive passes over out.
// ---------------------------------------------------------------------------
template<int K, int WS, int WOFF, bool GATHER, bool INIT, bool FINAL>
__global__ __launch_bounds__(256) void pass_kernel(
    const float* __restrict__ src, const int* __restrict__ gidx,
    const float* __restrict__ W, const float* __restrict__ beff,
    float* __restrict__ out, int E)
{
  int e = blockIdx.x * 256 + threadIdx.x;
  if (e >= E) return;
  long row = GATHER ? (long)gidx[e] : (long)e;

  float4 rv[K / 4];
  const float4* sp = (const float4*)(src + row * K);
  #pragma unroll
  for (int c = 0; c < K / 4; ++c) rv[c] = sp[c];

  float* orow = out + (long)e * D;
  for (int ob = 0; ob < D; ob += 4) {
    float acc[4];
    if (INIT) {
      float4 b4 = *(const float4*)&beff[ob];
      acc[0] = b4.x; acc[1] = b4.y; acc[2] = b4.z; acc[3] = b4.w;
    } else {
      float4 p4 = *(const float4*)&orow[ob];
      acc[0] = p4.x; acc[1] = p4.y; acc[2] = p4.z; acc[3] = p4.w;
    }
    #pragma unroll
    for (int k = 0; k < 4; ++k) {
      const float4* wv = (const float4*)&W[(long)(ob + k) * WS + WOFF];
      float a = acc[k];
      #pragma unroll
      for (int c = 0; c < K / 4; ++c) {
        float4 w4 = wv[c]; float4 r4 = rv[c];
        a = fmaf(w4.x, r4.x, a); a = fmaf(w4.y, r4.y, a);
        a = fmaf(w4.z, r4.z, a); a = fmaf(w4.w, r4.w, a);
      }
      acc[k] = a;
    }
    float4 o4;
    o4.x = FINAL ? ssp_f(acc[0]) : acc[0];
    o4.y = FINAL ? ssp_f(acc[1]) : acc[1];
    o4.z = FINAL ? ssp_f(acc[2]) : acc[2];
    o4.w = FINAL ? ssp_f(acc[3]) : acc[3];
    *(float4*)&orow[ob] = o4;
  }
}

// ---------------------------------------------------------------------------
extern "C" void kernel_launch(void* const* d_in, const int* in_sizes, int n_in,
                              void* d_out, int out_size, void* d_ws, size_t ws_size,
                              hipStream_t stream)
{
  const float* vi    = (const float*)d_in[0];
  const float* rbf   = (const float*)d_in[1];
  const float* W_rbf = (const float*)d_in[2];
  const float* b_rbf = (const float*)d_in[3];
  const float* W_cat = (const float*)d_in[4];
  const float* b_cat = (const float*)d_in[5];
  const int*   eidx  = (const int*)d_in[6];

  const int N = in_sizes[0] / D;
  const int E = in_sizes[6] / 2;
  float* out = (float*)d_out;

  float* ws   = (float*)d_ws;
  float* weff = ws;                 // 128*64 = 8192 floats
  float* beff = ws + D * DR;        // 128 floats
  float* Pj   = ws + 8448;          // N*128 floats, 16B-aligned
  float* Pi   = Pj + (size_t)N * D;
  size_t need = (8448 + 2 * (size_t)N * D) * sizeof(float);

  stage0_kernel<<<32, 256, 0, stream>>>(W_rbf, b_rbf, W_cat, b_cat, weff, beff);

  if (ws_size >= need && E >= 8) {
    stage1_kernel<<<(N + NB - 1) / NB, 256, 0, stream>>>(vi, W_cat, Pj, Pi, N);
    int fblocks = (int)(((long)E + 1023) / 1024);   // 4 waves x 256 edges per block
    fused_kernel<<<fblocks, 256, 0, stream>>>(rbf, eidx, weff, beff, Pj, Pi, out, E);
  } else {
    int eblocks = (E + 255) / 256;
    pass_kernel<DR, DR, 0,  false, true,  false><<<eblocks, 256, 0, stream>>>(rbf, nullptr,  weff,  beff, out, E);
    pass_kernel<D, 384, 128, true, false, false><<<eblocks, 256, 0, stream>>>(vi,  eidx + E, W_cat, beff, out, E);
    pass_kernel<D, 384, 256, true, false, true ><<<eblocks, 256, 0, stream>>>(vi,  eidx,     W_cat, beff, out, E);
  }
}

// Round 10
// 375.850 us; speedup vs baseline: 2.4519x; 1.2874x over previous
//
#include <hip/hip_runtime.h>
#include <cmath>

#define D  128   // D_EDGE
#define DR 64    // D_RBF
#define NB 32    // nodes per block in stage1

typedef float fx4 __attribute__((ext_vector_type(4)));

__device__ __forceinline__ float ssp_f(float x) {
  // softplus(x) - log(2), numerically stable
  float m = fmaxf(x, 0.0f);
  float t = __expf(-fabsf(x));
  return m + __logf(1.0f + t) - 0.69314718055994531f;
}

// ---------------------------------------------------------------------------
// stage0: W_eff[o][r] = sum_d W_cat[o][d] * W_rbf[d][r]   (128 x 64)
//         b_eff[o]    = b_cat[o] + sum_d b_rbf[d] * W_cat[o][d]
// ---------------------------------------------------------------------------
__global__ __launch_bounds__(256) void stage0_kernel(
    const float* __restrict__ W_rbf, const float* __restrict__ b_rbf,
    const float* __restrict__ W_cat, const float* __restrict__ b_cat,
    float* __restrict__ weff, float* __restrict__ beff)
{
  int gid = blockIdx.x * 256 + threadIdx.x;
  if (gid < D * DR) {
    int o = gid >> 6;
    int r = gid & 63;
    float acc = 0.0f;
    #pragma unroll 8
    for (int d = 0; d < D; ++d)
      acc = fmaf(W_cat[o * 384 + d], W_rbf[d * DR + r], acc);
    weff[gid] = acc;
  }
  if (gid < D) {
    float acc = b_cat[gid];
    #pragma unroll 8
    for (int d = 0; d < D; ++d)
      acc = fmaf(b_rbf[d], W_cat[gid * 384 + d], acc);
    beff[gid] = acc;
  }
}

// ---------------------------------------------------------------------------
// stage1: Pj[n][o] = sum_d vi[n][d] * W_cat[o][128+d]
//         Pi[n][o] = sum_d vi[n][d] * W_cat[o][256+d]
// ---------------------------------------------------------------------------
__global__ __launch_bounds__(256) void stage1_kernel(
    const float* __restrict__ vi, const float* __restrict__ W_cat,
    float* __restrict__ Pj, float* __restrict__ Pi, int N)
{
  __shared__ float vrow[NB * D];
  int base = blockIdx.x * NB;
  int t = threadIdx.x;
  for (int idx = t * 4; idx < NB * D; idx += 1024) {
    int n = base + (idx >> 7);
    float4 v = make_float4(0.f, 0.f, 0.f, 0.f);
    if (n < N) v = *(const float4*)&vi[(long)n * D + (idx & 127)];
    *(float4*)&vrow[idx] = v;
  }
  __syncthreads();

  int o     = t & 127;
  int which = t >> 7;
  const float* w = W_cat + (long)o * 384 + 128 + which * 128;
  float* P = which ? Pi : Pj;

  float acc[NB];
  #pragma unroll
  for (int n = 0; n < NB; ++n) acc[n] = 0.0f;

  for (int dd = 0; dd < D; dd += 4) {
    float4 wv = *(const float4*)&w[dd];
    #pragma unroll
    for (int n = 0; n < NB; ++n) {
      float4 v = *(const float4*)&vrow[n * D + dd];
      acc[n] = fmaf(wv.x, v.x, acc[n]);
      acc[n] = fmaf(wv.y, v.y, acc[n]);
      acc[n] = fmaf(wv.z, v.z, acc[n]);
      acc[n] = fmaf(wv.w, v.w, acc[n]);
    }
  }
  #pragma unroll
  for (int n = 0; n < NB; ++n) {
    int nn = base + n;
    if (nn < N) P[(long)nn * D + o] = acc[n];
  }
}

// ---------------------------------------------------------------------------
// Fused transposed kernel v2. Wave-autonomous (NO barriers).
//   lane = ONE output channel o = (gw&1)*64 + lane  (weights: 64 VGPR)
//   wave = 128-edge strip (gw>>1), 16 groups of 8 edges; 2 waves/strip
//   cover the two channel halves.
// Per group: rbf staged coalesced -> wave-private LDS (uniform broadcast
// reads); Pj/Pi gathers = coalesced 256B row reads (1 float/lane/edge);
// stores coalesced 256B. Depth-2 pipeline with sched_barrier(0) pinning
// the load-issue points (R6/R9: scheduler otherwise sinks gathers to use;
// R10's halved footprint makes everything fit in ~140 VGPR so the compiler
// doesn't have to sink or spill).
// ---------------------------------------------------------------------------
__device__ __forceinline__ void idx_load(const int* __restrict__ eidx, int E,
                                         long wbase, int g, int lane,
                                         int& jv, int& iv) {
  long gb = wbase + (long)g * 8 + (lane & 7);
  if (gb > (long)E - 1) gb = (long)E - 1;
  jv = eidx[(long)E + gb];   // edge_index[1] -> h_j -> Pj
  iv = eidx[gb];             // edge_index[0] -> h_i -> Pi
}

__device__ __forceinline__ void gather8h(const float* __restrict__ Pj,
                                         const float* __restrict__ Pi,
                                         int o, int jv, int iv,
                                         float* gj, float* gi) {
  #pragma unroll
  for (int e2 = 0; e2 < 8; ++e2) {
    int j = __builtin_amdgcn_readlane(jv, e2);   // SGPR base -> cheap addr
    int i = __builtin_amdgcn_readlane(iv, e2);
    gj[e2] = Pj[(long)j * D + o];
    gi[e2] = Pi[(long)i * D + o];
  }
}

__device__ __forceinline__ void stage_load(const float* __restrict__ rbf, int E,
                                           long wbase, int g, int lane,
                                           fx4& s0, fx4& s1) {
  long sb = wbase + (long)g * 8;
  if (sb + 8 > (long)E) sb = (long)E - 8;
  const float* src = &rbf[sb * DR];
  s0 = *(const fx4*)&src[lane * 8];
  s1 = *(const fx4*)&src[lane * 8 + 4];
}

__device__ __forceinline__ void compute_group(
    const float* buf, const fx4* wq, float b0,
    const float* gj, const float* gi,
    float* __restrict__ out, int E, long wbase, int g, int o) {
  #pragma unroll
  for (int e2 = 0; e2 < 8; ++e2) {
    const float* row = &buf[e2 * DR];
    float acc = b0;
    #pragma unroll
    for (int c = 0; c < 16; ++c) {
      fx4 r = *(const fx4*)&row[c * 4];   // wave-uniform -> LDS broadcast
      fx4 wv = wq[c];
      acc = fmaf(wv.x, r.x, acc); acc = fmaf(wv.y, r.y, acc);
      acc = fmaf(wv.z, r.z, acc); acc = fmaf(wv.w, r.w, acc);
    }
    long ge = wbase + (long)g * 8 + e2;
    if (ge < (long)E)
      out[ge * D + o] = ssp_f(acc + gj[e2] + gi[e2]);
  }
}

__global__ __launch_bounds__(256) void fused_kernel(
    const float* __restrict__ rbf, const int* __restrict__ eidx,
    const float* __restrict__ weff, const float* __restrict__ beff,
    const float* __restrict__ Pj, const float* __restrict__ Pi,
    float* __restrict__ out, int E)
{
  __shared__ float lds[4][2][512];   // 4 waves x 2 bufs x (8 edges x 64) = 16 KB

  const int t = threadIdx.x;
  const int w = t >> 6, lane = t & 63;
  const long gw = (long)blockIdx.x * 4 + w;
  const long wbase = (gw >> 1) * 128;          // 128-edge strip
  const int o = (int)(gw & 1) * 64 + lane;     // this lane's output channel
  if (wbase >= (long)E) return;

  // weights: lane holds W_eff row o (64 VGPRs) + bias
  fx4 wq[16];
  #pragma unroll
  for (int c = 0; c < 16; ++c) wq[c] = *(const fx4*)&weff[o * DR + c * 4];
  const float b0 = beff[o];

  float* buf0 = lds[w][0];
  float* buf1 = lds[w][1];

  int jvA, ivA, jvB, ivB;
  float gjA[8], giA[8], gjB[8], giB[8];
  fx4 sA0, sA1, sB0, sB1;

  // prologue: group 0 staged + gathered, group-1 indices in flight
  idx_load(eidx, E, wbase, 0, lane, jvA, ivA);
  idx_load(eidx, E, wbase, 1, lane, jvB, ivB);
  stage_load(rbf, E, wbase, 0, lane, sA0, sA1);
  gather8h(Pj, Pi, o, jvA, ivA, gjA, giA);
  *(fx4*)&buf0[lane * 8] = sA0;
  *(fx4*)&buf0[lane * 8 + 4] = sA1;

  for (int g = 0; g < 16; g += 2) {
    // issue group g+1 loads; prefetch indices for g+2
    stage_load(rbf, E, wbase, g + 1, lane, sB0, sB1);
    gather8h(Pj, Pi, o, jvB, ivB, gjB, giB);
    idx_load(eidx, E, wbase, g + 2, lane, jvA, ivA);
    __builtin_amdgcn_sched_barrier(0);   // pin: loads issued before compute

    compute_group(buf0, wq, b0, gjA, giA, out, E, wbase, g, o);

    *(fx4*)&buf1[lane * 8] = sB0;        // rbf g+1 landed during compute
    *(fx4*)&buf1[lane * 8 + 4] = sB1;

    // issue group g+2 loads; prefetch indices for g+3
    stage_load(rbf, E, wbase, g + 2, lane, sA0, sA1);
    gather8h(Pj, Pi, o, jvA, ivA, gjA, giA);
    idx_load(eidx, E, wbase, g + 3, lane, jvB, ivB);
    __builtin_amdgcn_sched_barrier(0);   // pin

    compute_group(buf1, wq, b0, gjB, giB, out, E, wbase, g + 1, o);

    *(fx4*)&buf0[lane * 8] = sA0;
    *(fx4*)&buf0[lane * 8 + 4] = sA1;
  }
}

// ---------------------------------------------------------------------------
// Fallback (only if d_ws is too small for Pj/Pi): 3 additive passes over out.
// ---------------------------------------------------------------------------
template<int K, int WS, int WOFF, bool GATHER, bool INIT, bool FINAL>
__global__ __launch_bounds__(256) void pass_kernel(
    const float* __restrict__ src, const int* __restrict__ gidx,
    const float* __restrict__ W, const float* __restrict__ beff,
    float* __restrict__ out, int E)
{
  int e = blockIdx.x * 256 + threadIdx.x;
  if (e >= E) return;
  long row = GATHER ? (long)gidx[e] : (long)e;

  float4 rv[K / 4];
  const float4* sp = (const float4*)(src + row * K);
  #pragma unroll
  for (int c = 0; c < K / 4; ++c) rv[c] = sp[c];

  float* orow = out + (long)e * D;
  for (int ob = 0; ob < D; ob += 4) {
    float acc[4];
    if (INIT) {
      float4 b4 = *(const float4*)&beff[ob];
      acc[0] = b4.x; acc[1] = b4.y; acc[2] = b4.z; acc[3] = b4.w;
    } else {
      float4 p4 = *(const float4*)&orow[ob];
      acc[0] = p4.x; acc[1] = p4.y; acc[2] = p4.z; acc[3] = p4.w;
    }
    #pragma unroll
    for (int k = 0; k < 4; ++k) {
      const float4* wv = (const float4*)&W[(long)(ob + k) * WS + WOFF];
      float a = acc[k];
      #pragma unroll
      for (int c = 0; c < K / 4; ++c) {
        float4 w4 = wv[c]; float4 r4 = rv[c];
        a = fmaf(w4.x, r4.x, a); a = fmaf(w4.y, r4.y, a);
        a = fmaf(w4.z, r4.z, a); a = fmaf(w4.w, r4.w, a);
      }
      acc[k] = a;
    }
    float4 o4;
    o4.x = FINAL ? ssp_f(acc[0]) : acc[0];
    o4.y = FINAL ? ssp_f(acc[1]) : acc[1];
    o4.z = FINAL ? ssp_f(acc[2]) : acc[2];
    o4.w = FINAL ? ssp_f(acc[3]) : acc[3];
    *(float4*)&orow[ob] = o4;
  }
}

// ---------------------------------------------------------------------------
extern "C" void kernel_launch(void* const* d_in, const int* in_sizes, int n_in,
                              void* d_out, int out_size, void* d_ws, size_t ws_size,
                              hipStream_t stream)
{
  const float* vi    = (const float*)d_in[0];
  const float* rbf   = (const float*)d_in[1];
  const float* W_rbf = (const float*)d_in[2];
  const float* b_rbf = (const float*)d_in[3];
  const float* W_cat = (const float*)d_in[4];
  const float* b_cat = (const float*)d_in[5];
  const int*   eidx  = (const int*)d_in[6];

  const int N = in_sizes[0] / D;
  const int E = in_sizes[6] / 2;
  float* out = (float*)d_out;

  float* ws   = (float*)d_ws;
  float* weff = ws;                 // 128*64 = 8192 floats
  float* beff = ws + D * DR;        // 128 floats
  float* Pj   = ws + 8448;          // N*128 floats, 16B-aligned
  float* Pi   = Pj + (size_t)N * D;
  size_t need = (8448 + 2 * (size_t)N * D) * sizeof(float);

  stage0_kernel<<<32, 256, 0, stream>>>(W_rbf, b_rbf, W_cat, b_cat, weff, beff);

  if (ws_size >= need && E >= 8) {
    stage1_kernel<<<(N + NB - 1) / NB, 256, 0, stream>>>(vi, W_cat, Pj, Pi, N);
    long strips = ((long)E + 127) / 128;
    long waves  = strips * 2;
    int fblocks = (int)((waves + 3) / 4);
    fused_kernel<<<fblocks, 256, 0, stream>>>(rbf, eidx, weff, beff, Pj, Pi, out, E);
  } else {
    int eblocks = (E + 255) / 256;
    pass_kernel<DR, DR, 0,  false, true,  false><<<eblocks, 256, 0, stream>>>(rbf, nullptr,  weff,  beff, out, E);
    pass_kernel<D, 384, 128, true, false, false><<<eblocks, 256, 0, stream>>>(vi,  eidx + E, W_cat, beff, out, E);
    pass_kernel<D, 384, 256, true, false, true ><<<eblocks, 256, 0, stream>>>(vi,  eidx,     W_cat, beff, out, E);
  }
}

// Round 11
// 287.050 us; speedup vs baseline: 3.2104x; 1.3094x over previous
//
#include <hip/hip_runtime.h>
#include <cmath>

#define D  128   // D_EDGE
#define DR 64    // D_RBF
#define NB 32    // nodes per block in stage1

typedef float fx4    __attribute__((ext_vector_type(4)));
typedef float f32x16 __attribute__((ext_vector_type(16)));
typedef short short8v __attribute__((ext_vector_type(8)));

__device__ __forceinline__ float ssp_f(float x) {
  // softplus(x) - log(2), numerically stable
  float m = fmaxf(x, 0.0f);
  float t = __expf(-fabsf(x));
  return m + __logf(1.0f + t) - 0.69314718055994531f;
}

__device__ __forceinline__ short f2bf(float f) {   // fp32 -> bf16 (RNE)
  unsigned u = __float_as_uint(f);
  u = (u + 0x7FFFu + ((u >> 16) & 1u)) >> 16;
  return (short)u;
}

// ---------------------------------------------------------------------------
// stage0: W_eff = W_cat[:, :128] @ W_rbf (128x64), b_eff; also bf16 copy.
// ---------------------------------------------------------------------------
__global__ __launch_bounds__(256) void stage0_kernel(
    const float* __restrict__ W_rbf, const float* __restrict__ b_rbf,
    const float* __restrict__ W_cat, const float* __restrict__ b_cat,
    float* __restrict__ weff, unsigned short* __restrict__ weffh,
    float* __restrict__ beff, int write_bf16)
{
  int gid = blockIdx.x * 256 + threadIdx.x;
  if (gid < D * DR) {
    int o = gid >> 6;
    int r = gid & 63;
    float acc = 0.0f;
    #pragma unroll 8
    for (int d = 0; d < D; ++d)
      acc = fmaf(W_cat[o * 384 + d], W_rbf[d * DR + r], acc);
    weff[gid] = acc;
    if (write_bf16) weffh[gid] = (unsigned short)f2bf(acc);
  }
  if (gid < D) {
    float acc = b_cat[gid];
    #pragma unroll 8
    for (int d = 0; d < D; ++d)
      acc = fmaf(b_rbf[d], W_cat[gid * 384 + d], acc);
    beff[gid] = acc;
  }
}

// ---------------------------------------------------------------------------
// stage1: Pj[n][o] = vi[n] . W_cat[o][128:256], Pi[n][o] = vi[n] . W_cat[o][256:384]
// ---------------------------------------------------------------------------
__global__ __launch_bounds__(256) void stage1_kernel(
    const float* __restrict__ vi, const float* __restrict__ W_cat,
    float* __restrict__ Pj, float* __restrict__ Pi, int N)
{
  __shared__ float vrow[NB * D];
  int base = blockIdx.x * NB;
  int t = threadIdx.x;
  for (int idx = t * 4; idx < NB * D; idx += 1024) {
    int n = base + (idx >> 7);
    float4 v = make_float4(0.f, 0.f, 0.f, 0.f);
    if (n < N) v = *(const float4*)&vi[(long)n * D + (idx & 127)];
    *(float4*)&vrow[idx] = v;
  }
  __syncthreads();

  int o     = t & 127;
  int which = t >> 7;
  const float* w = W_cat + (long)o * 384 + 128 + which * 128;
  float* P = which ? Pi : Pj;

  float acc[NB];
  #pragma unroll
  for (int n = 0; n < NB; ++n) acc[n] = 0.0f;

  for (int dd = 0; dd < D; dd += 4) {
    float4 wv = *(const float4*)&w[dd];
    #pragma unroll
    for (int n = 0; n < NB; ++n) {
      float4 v = *(const float4*)&vrow[n * D + dd];
      acc[n] = fmaf(wv.x, v.x, acc[n]);
      acc[n] = fmaf(wv.y, v.y, acc[n]);
      acc[n] = fmaf(wv.z, v.z, acc[n]);
      acc[n] = fmaf(wv.w, v.w, acc[n]);
    }
  }
  #pragma unroll
  for (int n = 0; n < NB; ++n) {
    int nn = base + n;
    if (nn < N) P[(long)nn * D + o] = acc[n];
  }
}

// ---------------------------------------------------------------------------
// MFMA edge kernel. Wave-autonomous, NO LDS, NO barriers.
//   wave = 64 edges (2 tiles of 32). mfma_f32_32x32x16_bf16:
//   A[m=edge][k=rbf], B[k][n=chan]; C/D: col=lane&31, row=(reg&3)+8*(reg>>2)
//   +4*(lane>>5) [HW-verified layout]. k-order chosen identically for A and B
//   (k = ks*16 + 8*half + i) -> result independent of HW's internal k map.
// B-frags (all 128 chans x K=64 as bf16) live in 64 VGPR, loaded once/wave.
// Epilogue in C/D layout: gathers/stores are full 128B lines
// (lanes 0-31 = 32 consecutive channels of one edge row).
// ---------------------------------------------------------------------------
__global__ __launch_bounds__(256) void edge_mfma_kernel(
    const float* __restrict__ rbf, const int* __restrict__ eidx,
    const unsigned short* __restrict__ weffh, const float* __restrict__ beff,
    const float* __restrict__ Pj, const float* __restrict__ Pi,
    float* __restrict__ out, int E)
{
  const int t    = threadIdx.x;
  const int lane = t & 63;
  const int row  = lane & 31;   // A row / B col / C col
  const int half = lane >> 5;   // k-half selector
  const long wid  = (long)blockIdx.x * 4 + (t >> 6);
  const long base = wid * 64;
  if (base >= (long)E) return;

  // B fragments: B[k][n] = weff[n*64+k] (bf16), n=ct*32+row, k=ks*16+8*half+i
  short8v B[4][4];
  #pragma unroll
  for (int ct = 0; ct < 4; ++ct) {
    #pragma unroll
    for (int ks = 0; ks < 4; ++ks)
      B[ct][ks] = *(const short8v*)&weffh[(ct * 32 + row) * DR + ks * 16 + half * 8];
  }
  float bias[4];
  #pragma unroll
  for (int ct = 0; ct < 4; ++ct) bias[ct] = beff[ct * 32 + row];

  #pragma unroll
  for (int tile = 0; tile < 2; ++tile) {
    const long tb = base + (long)tile * 32;
    if (tb >= (long)E) break;
    long er = tb + row; if (er > (long)E - 1) er = (long)E - 1;

    // A fragments straight from global (fp32 -> bf16); rows L1/L2-cached
    const float* arow = rbf + er * DR + half * 8;
    short8v A[4];
    #pragma unroll
    for (int ks = 0; ks < 4; ++ks) {
      fx4 lo = *(const fx4*)&arow[ks * 16];
      fx4 hi = *(const fx4*)&arow[ks * 16 + 4];
      short8v a;
      a[0] = f2bf(lo.x); a[1] = f2bf(lo.y); a[2] = f2bf(lo.z); a[3] = f2bf(lo.w);
      a[4] = f2bf(hi.x); a[5] = f2bf(hi.y); a[6] = f2bf(hi.z); a[7] = f2bf(hi.w);
      A[ks] = a;
    }

    // per-lane edge indices for this tile (lane's row = local edge id)
    const int iv = eidx[er];            // edge_index[0] -> h_i -> Pi
    const int jv = eidx[(long)E + er];  // edge_index[1] -> h_j -> Pj

    #pragma unroll
    for (int ct = 0; ct < 4; ++ct) {
      // gathers for this chan-tile: 32 loads in flight (coalesced 128B lines)
      float gj[16], gi[16];
      #pragma unroll
      for (int reg = 0; reg < 16; ++reg) {
        const int erl = (reg & 3) + 8 * (reg >> 2) + 4 * half;
        const int j = __shfl(jv, erl);
        const int i = __shfl(iv, erl);
        gj[reg] = Pj[(long)j * D + ct * 32 + row];
        gi[reg] = Pi[(long)i * D + ct * 32 + row];
      }
      __builtin_amdgcn_sched_barrier(0);   // keep gather issue ahead of MFMA

      f32x16 acc = (f32x16)(0.0f);
      acc = __builtin_amdgcn_mfma_f32_32x32x16_bf16(A[0], B[ct][0], acc, 0, 0, 0);
      acc = __builtin_amdgcn_mfma_f32_32x32x16_bf16(A[1], B[ct][1], acc, 0, 0, 0);
      acc = __builtin_amdgcn_mfma_f32_32x32x16_bf16(A[2], B[ct][2], acc, 0, 0, 0);
      acc = __builtin_amdgcn_mfma_f32_32x32x16_bf16(A[3], B[ct][3], acc, 0, 0, 0);

      #pragma unroll
      for (int reg = 0; reg < 16; ++reg) {
        const int erl = (reg & 3) + 8 * (reg >> 2) + 4 * half;
        const long ge = tb + erl;
        const float v = ssp_f(acc[reg] + gj[reg] + gi[reg] + bias[ct]);
        if (ge < (long)E) out[ge * D + ct * 32 + row] = v;   // 128B lines
      }
    }
  }
}

// ---------------------------------------------------------------------------
// Fallback (only if d_ws is too small for Pj/Pi): 3 additive passes over out.
// ---------------------------------------------------------------------------
template<int K, int WS, int WOFF, bool GATHER, bool INIT, bool FINAL>
__global__ __launch_bounds__(256) void pass_kernel(
    const float* __restrict__ src, const int* __restrict__ gidx,
    const float* __restrict__ W, const float* __restrict__ beff,
    float* __restrict__ out, int E)
{
  int e = blockIdx.x * 256 + threadIdx.x;
  if (e >= E) return;
  long rowi = GATHER ? (long)gidx[e] : (long)e;

  float4 rv[K / 4];
  const float4* sp = (const float4*)(src + rowi * K);
  #pragma unroll
  for (int c = 0; c < K / 4; ++c) rv[c] = sp[c];

  float* orow = out + (long)e * D;
  for (int ob = 0; ob < D; ob += 4) {
    float acc[4];
    if (INIT) {
      float4 b4 = *(const float4*)&beff[ob];
      acc[0] = b4.x; acc[1] = b4.y; acc[2] = b4.z; acc[3] = b4.w;
    } else {
      float4 p4 = *(const float4*)&orow[ob];
      acc[0] = p4.x; acc[1] = p4.y; acc[2] = p4.z; acc[3] = p4.w;
    }
    #pragma unroll
    for (int k = 0; k < 4; ++k) {
      const float4* wv = (const float4*)&W[(long)(ob + k) * WS + WOFF];
      float a = acc[k];
      #pragma unroll
      for (int c = 0; c < K / 4; ++c) {
        float4 w4 = wv[c]; float4 r4 = rv[c];
        a = fmaf(w4.x, r4.x, a); a = fmaf(w4.y, r4.y, a);
        a = fmaf(w4.z, r4.z, a); a = fmaf(w4.w, r4.w, a);
      }
      acc[k] = a;
    }
    float4 o4;
    o4.x = FINAL ? ssp_f(acc[0]) : acc[0];
    o4.y = FINAL ? ssp_f(acc[1]) : acc[1];
    o4.z = FINAL ? ssp_f(acc[2]) : acc[2];
    o4.w = FINAL ? ssp_f(acc[3]) : acc[3];
    *(float4*)&orow[ob] = o4;
  }
}

// ---------------------------------------------------------------------------
extern "C" void kernel_launch(void* const* d_in, const int* in_sizes, int n_in,
                              void* d_out, int out_size, void* d_ws, size_t ws_size,
                              hipStream_t stream)
{
  const float* vi    = (const float*)d_in[0];
  const float* rbf   = (const float*)d_in[1];
  const float* W_rbf = (const float*)d_in[2];
  const float* b_rbf = (const float*)d_in[3];
  const float* W_cat = (const float*)d_in[4];
  const float* b_cat = (const float*)d_in[5];
  const int*   eidx  = (const int*)d_in[6];

  const int N = in_sizes[0] / D;
  const int E = in_sizes[6] / 2;
  float* out = (float*)d_out;

  float* ws   = (float*)d_ws;
  float* weff = ws;                               // 8192 floats
  float* beff = ws + D * DR;                      // 128 floats (ends 8320)
  unsigned short* weffh = (unsigned short*)(ws + 8448);  // 8192 ushort = 4096 floats
  float* Pj   = ws + 8448 + 4096;                 // N*128 floats
  float* Pi   = Pj + (size_t)N * D;
  size_t need = (8448 + 4096 + 2 * (size_t)N * D) * sizeof(float);

  const int use_fast = (ws_size >= need && E >= 1);
  stage0_kernel<<<32, 256, 0, stream>>>(W_rbf, b_rbf, W_cat, b_cat,
                                        weff, weffh, beff, use_fast);

  if (use_fast) {
    stage1_kernel<<<(N + NB - 1) / NB, 256, 0, stream>>>(vi, W_cat, Pj, Pi, N);
    long waves = ((long)E + 63) / 64;
    int fblocks = (int)((waves + 3) / 4);
    edge_mfma_kernel<<<fblocks, 256, 0, stream>>>(rbf, eidx, weffh, beff,
                                                  Pj, Pi, out, E);
  } else {
    int eblocks = (E + 255) / 256;
    pass_kernel<DR, DR, 0,  false, true,  false><<<eblocks, 256, 0, stream>>>(rbf, nullptr,  weff,  beff, out, E);
    pass_kernel<D, 384, 128, true, false, false><<<eblocks, 256, 0, stream>>>(vi,  eidx + E, W_cat, beff, out, E);
    pass_kernel<D, 384, 256, true, false, true ><<<eblocks, 256, 0, stream>>>(vi,  eidx,     W_cat, beff, out, E);
  }
}